// Round 7
// baseline (988.138 us; speedup 1.0000x reference)
//
#include <hip/hip_runtime.h>

typedef unsigned int u32;

static inline int idiv_up(int a, int b) { return (a + b - 1) / b; }

#define BSHIFT 11          // bucket width 2048 nodes
#define BW     2048
#define ACHUNK 8192        // edges per binA block

// ---------------- bf16 pack/unpack ----------------

__device__ __forceinline__ u32 pack_bf16_rne(float lo, float hi) {
    u32 ul = __float_as_uint(lo);
    u32 uh = __float_as_uint(hi);
    ul = (ul + 0x7fffu + ((ul >> 16) & 1u)) >> 16;
    uh = (uh + 0x7fffu + ((uh >> 16) & 1u));
    return (ul & 0xffffu) | (uh & 0xffff0000u);
}
__device__ __forceinline__ float bf16_lo(u32 u) { return __uint_as_float(u << 16); }
__device__ __forceinline__ float bf16_hi(u32 u) { return __uint_as_float(u & 0xffff0000u); }

// ---------------- degree histogram (int) ----------------

__global__ __launch_bounds__(256) void count_deg_kernel(
    const int* __restrict__ colL, const int* __restrict__ colN,
    int eL, int eN,
    int* __restrict__ degL, int* __restrict__ degN)
{
    int i = blockIdx.x * 256 + threadIdx.x;
    if (i < eL) atomicAdd(&degL[colL[i]], 1);
    if (i < eN) atomicAdd(&degN[colN[i]], 1);
}

__global__ __launch_bounds__(256) void dinv_kernel(
    const int* __restrict__ degL, const int* __restrict__ degN,
    float* __restrict__ dinvL, float* __restrict__ dinvN, int n)
{
    int i = blockIdx.x * 256 + threadIdx.x;
    if (i < n) {
        dinvL[i] = rsqrtf((float)degL[i] + 1.0f);   // +1 self loop
        dinvN[i] = rsqrtf((float)degN[i] + 1.0f);
    }
}

// ---------------- exclusive scan -> rowptr ----------------

__global__ __launch_bounds__(1024) void scan_kernel(
    const int* __restrict__ degL, const int* __restrict__ degN, int n,
    int* __restrict__ rowptrL, int* __restrict__ rowptrN)
{
    const int* deg = blockIdx.x ? degN : degL;
    int* rowptr    = blockIdx.x ? rowptrN : rowptrL;

    __shared__ int ls[1024];
    const int t = threadIdx.x;
    const int chunk = (n + 1023) / 1024;
    const int base = t * chunk;

    int s = 0;
    for (int i = 0; i < chunk; ++i) {
        int idx = base + i;
        if (idx < n) s += deg[idx];
    }
    ls[t] = s;
    __syncthreads();
    for (int off = 1; off < 1024; off <<= 1) {
        int add = (t >= off) ? ls[t - off] : 0;
        __syncthreads();
        ls[t] += add;
        __syncthreads();
    }
    int running = (t == 0) ? 0 : ls[t - 1];
    int total = ls[1023];
    for (int i = 0; i < chunk; ++i) {
        int idx = base + i;
        if (idx < n) {
            rowptr[idx] = running;
            running += deg[idx];
        }
    }
    if (t == 1023) rowptr[n] = total;
}

// ---------------- bucket cursor init: gcur[b] = rowptr[b*BW] ----------------

__global__ void init_gcur_kernel(
    const int* __restrict__ rowptrL, const int* __restrict__ rowptrN,
    int* __restrict__ gcurL, int* __restrict__ gcurN, int nb)
{
    int t = threadIdx.x;
    if (t < nb) {
        gcurL[t] = rowptrL[t << BSHIFT];
        gcurN[t] = rowptrN[t << BSHIFT];
    }
}

// ---------------- radix pass A: bin edges by dest-bucket ----------------

__global__ __launch_bounds__(256) void binA_kernel(
    const int* __restrict__ rowL, const int* __restrict__ colL, int eL,
    const int* __restrict__ rowN, const int* __restrict__ colN, int eN,
    int* __restrict__ gcurL, int* __restrict__ gcurN,
    uint2* __restrict__ stagedL, uint2* __restrict__ stagedN, int nb)
{
    const int adj = blockIdx.y;
    const int* rowA = adj ? rowN : rowL;
    const int* colA = adj ? colN : colL;
    const int e     = adj ? eN   : eL;
    int* gcur       = adj ? gcurN : gcurL;
    uint2* staged   = adj ? stagedN : stagedL;

    __shared__ int hist[64];
    __shared__ int base[64];
    const int t = threadIdx.x;
    if (t < 64) hist[t] = 0;
    __syncthreads();

    const int i0 = blockIdx.x * ACHUNK;
    const int i1 = min(i0 + ACHUNK, e);

    for (int i = i0 + t; i < i1; i += 256)
        atomicAdd(&hist[colA[i] >> BSHIFT], 1);
    __syncthreads();

    if (t < 64) {
        int cnt = hist[t];
        if (t < nb && cnt > 0) base[t] = atomicAdd(&gcur[t], cnt);
    }
    __syncthreads();
    if (t < 64) hist[t] = 0;    // reuse as per-bucket offset
    __syncthreads();

    for (int i = i0 + t; i < i1; i += 256) {
        int c = colA[i], r = rowA[i];
        int b = c >> BSHIFT;
        int pos = base[b] + atomicAdd(&hist[b], 1);
        staged[pos] = make_uint2((u32)c, (u32)r);
    }
}

// ---------------- radix pass B: place within bucket (LDS cursors) ----------------

__global__ __launch_bounds__(256) void binB_kernel(
    const int* __restrict__ rowptrL, const int* __restrict__ rowptrN,
    const uint2* __restrict__ stagedL, const uint2* __restrict__ stagedN,
    int* __restrict__ csrL, int* __restrict__ csrN, int n)
{
    const int adj = blockIdx.y;
    const int* rowptr   = adj ? rowptrN : rowptrL;
    const uint2* staged = adj ? stagedN : stagedL;
    int* csr            = adj ? csrN    : csrL;

    __shared__ int lcur[BW];
    const int lo = blockIdx.x << BSHIFT;
    const int hi = min(lo + BW, n);
    const int t = threadIdx.x;

    for (int i = lo + t; i < hi; i += 256) lcur[i - lo] = rowptr[i];
    __syncthreads();

    const int s0 = rowptr[lo], s1 = rowptr[hi];
    for (int i = s0 + t; i < s1; i += 256) {
        uint2 er = staged[i];
        int p = atomicAdd(&lcur[(int)er.x - lo], 1);
        csr[p] = (int)er.y;
    }
}

// ---------------- GEMM: y(bf16) = (A @ W) * dinv[row] ----------------

template<int NC>
__global__ __launch_bounds__(256) void gemm_kernel(
    const float* __restrict__ A, int n,
    const float* __restrict__ Wa, const float* __restrict__ Wb,
    const float* __restrict__ dinva, const float* __restrict__ dinvb,
    u32* __restrict__ ya, u32* __restrict__ yb,
    const float* __restrict__ bn_scale, const float* __restrict__ bn_shift)
{
    constexpr int K   = 128;
    constexpr int TR  = 64;        // rows per block
    constexpr int CG  = NC / 4;    // float4 column groups
    constexpr int TY  = 256 / CG;  // thread-row groups
    constexpr int RPT = TR / TY;   // rows per thread

    __shared__ float xs[TR][K];

    const float* W    = blockIdx.y ? Wb    : Wa;
    const float* dinv = blockIdx.y ? dinvb : dinva;
    u32* y            = blockIdx.y ? yb    : ya;

    const int row0 = blockIdx.x * TR;
    const int t = threadIdx.x;

    const float4* A4 = (const float4*)A;
    #pragma unroll
    for (int i = 0; i < (TR * (K / 4)) / 256; ++i) {
        int fl = i * 256 + t;
        int r  = fl >> 5;       // K/4 == 32
        int c4 = fl & 31;
        float4 v = make_float4(0.f, 0.f, 0.f, 0.f);
        int rr = row0 + r;
        if (rr < n) v = A4[(size_t)rr * 32 + c4];
        if (bn_scale) {
            float4 sc = ((const float4*)bn_scale)[c4];
            float4 sh = ((const float4*)bn_shift)[c4];
            v.x = fmaxf(v.x * sc.x + sh.x, 0.f);
            v.y = fmaxf(v.y * sc.y + sh.y, 0.f);
            v.z = fmaxf(v.z * sc.z + sh.z, 0.f);
            v.w = fmaxf(v.w * sc.w + sh.w, 0.f);
        }
        *(float4*)&xs[r][c4 * 4] = v;
    }
    __syncthreads();

    const int cg = t % CG;
    const int ty = t / CG;

    float4 accv[RPT];
    #pragma unroll
    for (int r = 0; r < RPT; ++r) accv[r] = make_float4(0.f, 0.f, 0.f, 0.f);

    const float4* W4 = (const float4*)W;
    for (int k = 0; k < K; k += 4) {
        float4 w0 = W4[(size_t)(k + 0) * CG + cg];
        float4 w1 = W4[(size_t)(k + 1) * CG + cg];
        float4 w2 = W4[(size_t)(k + 2) * CG + cg];
        float4 w3 = W4[(size_t)(k + 3) * CG + cg];
        #pragma unroll
        for (int r = 0; r < RPT; ++r) {
            float4 a = *(const float4*)&xs[ty * RPT + r][k];
            accv[r].x += a.x * w0.x; accv[r].y += a.x * w0.y; accv[r].z += a.x * w0.z; accv[r].w += a.x * w0.w;
            accv[r].x += a.y * w1.x; accv[r].y += a.y * w1.y; accv[r].z += a.y * w1.z; accv[r].w += a.y * w1.w;
            accv[r].x += a.z * w2.x; accv[r].y += a.z * w2.y; accv[r].z += a.z * w2.z; accv[r].w += a.z * w2.w;
            accv[r].x += a.w * w3.x; accv[r].y += a.w * w3.y; accv[r].z += a.w * w3.z; accv[r].w += a.w * w3.w;
        }
    }

    #pragma unroll
    for (int r = 0; r < RPT; ++r) {
        int rr = row0 + ty * RPT + r;
        if (rr < n) {
            float dv = dinv[rr];
            float4 o = accv[r];
            o.x *= dv; o.y *= dv; o.z *= dv; o.w *= dv;
            uint2 pk;
            pk.x = pack_bf16_rne(o.x, o.y);
            pk.y = pack_bf16_rne(o.z, o.w);
            ((uint2*)y)[(size_t)rr * CG + cg] = pk;
        }
    }
}

// ---------------- fused gather + combine (+bias, BN stats) ----------------
// Wave-cooperative index fetch: lane l of the CHW-lane group loads csr[j0+l]
// (one coalesced transaction = CHW indices), then __shfl broadcasts each.
// Row loads are issued 8 at a time with indices already in-register, so the
// only latency chain per iteration is the row loads themselves.

template<int CH, bool STATS>
__global__ __launch_bounds__(256) void gather_kernel(
    const int* __restrict__ rowptrL, const int* __restrict__ csrL,
    const int* __restrict__ rowptrN, const int* __restrict__ csrN,
    const u32* __restrict__ yL, const u32* __restrict__ yN,
    const float* __restrict__ dinvL, const float* __restrict__ dinvN,
    const float* __restrict__ bL, const float* __restrict__ bN,
    float* __restrict__ out, int n,
    float* __restrict__ bn_sum, float* __restrict__ bn_sumsq)
{
    constexpr int CHW = CH / 2;         // u32 lanes per node (also idx batch)
    constexpr int NPB = 256 / CHW;      // nodes per block-iteration
    const int c  = threadIdx.x % CHW;
    const int ns = threadIdx.x / CHW;
    const float2 blv = ((const float2*)bL)[c];
    const float2 bnv = ((const float2*)bN)[c];

    float s0 = 0.f, s1 = 0.f, q0 = 0.f, q1 = 0.f;

    for (int node0 = blockIdx.x * NPB; node0 < n; node0 += gridDim.x * NPB) {
        const int node = node0 + ns;
        if (node < n) {
            u32 uself = yL[(size_t)node * CHW + c];
            float sL0 = bf16_lo(uself), sL1 = bf16_hi(uself);
            {
                int j0 = rowptrL[node], end = rowptrL[node + 1];
                for (int base = j0; base < end; base += CHW) {
                    int myidx = (base + c < end) ? csrL[base + c] : 0;
                    int m = min(CHW, end - base);
                    int k = 0;
                    for (; k + 8 <= m; k += 8) {
                        int u0 = __shfl(myidx, k + 0, CHW);
                        int u1 = __shfl(myidx, k + 1, CHW);
                        int u2 = __shfl(myidx, k + 2, CHW);
                        int u3 = __shfl(myidx, k + 3, CHW);
                        int u4 = __shfl(myidx, k + 4, CHW);
                        int u5 = __shfl(myidx, k + 5, CHW);
                        int u6 = __shfl(myidx, k + 6, CHW);
                        int u7 = __shfl(myidx, k + 7, CHW);
                        u32 a0 = yL[(size_t)u0 * CHW + c];
                        u32 a1 = yL[(size_t)u1 * CHW + c];
                        u32 a2 = yL[(size_t)u2 * CHW + c];
                        u32 a3 = yL[(size_t)u3 * CHW + c];
                        u32 a4 = yL[(size_t)u4 * CHW + c];
                        u32 a5 = yL[(size_t)u5 * CHW + c];
                        u32 a6 = yL[(size_t)u6 * CHW + c];
                        u32 a7 = yL[(size_t)u7 * CHW + c];
                        sL0 += bf16_lo(a0) + bf16_lo(a1) + bf16_lo(a2) + bf16_lo(a3)
                             + bf16_lo(a4) + bf16_lo(a5) + bf16_lo(a6) + bf16_lo(a7);
                        sL1 += bf16_hi(a0) + bf16_hi(a1) + bf16_hi(a2) + bf16_hi(a3)
                             + bf16_hi(a4) + bf16_hi(a5) + bf16_hi(a6) + bf16_hi(a7);
                    }
                    for (; k < m; ++k) {
                        int u = __shfl(myidx, k, CHW);
                        u32 a = yL[(size_t)u * CHW + c];
                        sL0 += bf16_lo(a); sL1 += bf16_hi(a);
                    }
                }
            }
            u32 vself = yN[(size_t)node * CHW + c];
            float sN0 = bf16_lo(vself), sN1 = bf16_hi(vself);
            {
                int j0 = rowptrN[node], end = rowptrN[node + 1];
                for (int base = j0; base < end; base += CHW) {
                    int myidx = (base + c < end) ? csrN[base + c] : 0;
                    int m = min(CHW, end - base);
                    int k = 0;
                    for (; k + 8 <= m; k += 8) {
                        int u0 = __shfl(myidx, k + 0, CHW);
                        int u1 = __shfl(myidx, k + 1, CHW);
                        int u2 = __shfl(myidx, k + 2, CHW);
                        int u3 = __shfl(myidx, k + 3, CHW);
                        int u4 = __shfl(myidx, k + 4, CHW);
                        int u5 = __shfl(myidx, k + 5, CHW);
                        int u6 = __shfl(myidx, k + 6, CHW);
                        int u7 = __shfl(myidx, k + 7, CHW);
                        u32 a0 = yN[(size_t)u0 * CHW + c];
                        u32 a1 = yN[(size_t)u1 * CHW + c];
                        u32 a2 = yN[(size_t)u2 * CHW + c];
                        u32 a3 = yN[(size_t)u3 * CHW + c];
                        u32 a4 = yN[(size_t)u4 * CHW + c];
                        u32 a5 = yN[(size_t)u5 * CHW + c];
                        u32 a6 = yN[(size_t)u6 * CHW + c];
                        u32 a7 = yN[(size_t)u7 * CHW + c];
                        sN0 += bf16_lo(a0) + bf16_lo(a1) + bf16_lo(a2) + bf16_lo(a3)
                             + bf16_lo(a4) + bf16_lo(a5) + bf16_lo(a6) + bf16_lo(a7);
                        sN1 += bf16_hi(a0) + bf16_hi(a1) + bf16_hi(a2) + bf16_hi(a3)
                             + bf16_hi(a4) + bf16_hi(a5) + bf16_hi(a6) + bf16_hi(a7);
                    }
                    for (; k < m; ++k) {
                        int u = __shfl(myidx, k, CHW);
                        u32 a = yN[(size_t)u * CHW + c];
                        sN0 += bf16_lo(a); sN1 += bf16_hi(a);
                    }
                }
            }
            float dl = dinvL[node], dn = dinvN[node];
            float v0 = dl * sL0 + blv.x + 0.5f * (dn * sN0 + bnv.x);
            float v1 = dl * sL1 + blv.y + 0.5f * (dn * sN1 + bnv.y);
            ((float2*)out)[(size_t)node * CHW + c] = make_float2(v0, v1);
            if constexpr (STATS) { s0 += v0; s1 += v1; q0 += v0 * v0; q1 += v1 * v1; }
        }
    }

    if constexpr (STATS) {
        __shared__ float4 ls[256];
        ls[threadIdx.x] = make_float4(s0, s1, q0, q1);
        __syncthreads();
        if (threadIdx.x < CHW) {
            float4 a = ls[threadIdx.x];
            #pragma unroll
            for (int i = 1; i < NPB; ++i) {
                float4 b = ls[threadIdx.x + i * CHW];
                a.x += b.x; a.y += b.y; a.z += b.z; a.w += b.w;
            }
            atomicAdd(&bn_sum[2 * threadIdx.x + 0], a.x);
            atomicAdd(&bn_sum[2 * threadIdx.x + 1], a.y);
            atomicAdd(&bn_sumsq[2 * threadIdx.x + 0], a.z);
            atomicAdd(&bn_sumsq[2 * threadIdx.x + 1], a.w);
        }
    }
}

__global__ void bn_final_kernel(
    const float* __restrict__ sum, const float* __restrict__ sumsq,
    const float* __restrict__ gamma, const float* __restrict__ beta,
    float* __restrict__ scale, float* __restrict__ shift, float inv_n)
{
    int c = threadIdx.x;
    float mean = sum[c] * inv_n;
    float var  = sumsq[c] * inv_n - mean * mean;
    float sc = gamma[c] * rsqrtf(var + 1e-5f);
    scale[c] = sc;
    shift[c] = beta[c] - mean * sc;
}

// ---------------- launch ----------------

extern "C" void kernel_launch(void* const* d_in, const int* in_sizes, int n_in,
                              void* d_out, int out_size, void* d_ws, size_t ws_size,
                              hipStream_t stream)
{
    const float* x     = (const float*)d_in[0];
    const int*   adjL  = (const int*)d_in[1];   // adj_low
    const int*   adjN  = (const int*)d_in[3];   // adj_nd_low (adj_high/nd_high unused)
    const float* W1L   = (const float*)d_in[5];
    const float* b1L   = (const float*)d_in[6];
    const float* W1N   = (const float*)d_in[7];
    const float* b1N   = (const float*)d_in[8];
    const float* gamma = (const float*)d_in[9];
    const float* beta  = (const float*)d_in[10];
    const float* W2L   = (const float*)d_in[11];
    const float* b2L   = (const float*)d_in[12];
    const float* W2N   = (const float*)d_in[13];
    const float* b2N   = (const float*)d_in[14];

    const int n  = in_sizes[0] / 128;
    const int eL = in_sizes[1] / 2;
    const int eN = in_sizes[3] / 2;
    const int* rowL = adjL;  const int* colL = adjL + eL;
    const int* rowN = adjN;  const int* colN = adjN + eN;
    const int nb = idiv_up(n, BW);

    char* p = (char*)d_ws;
    const size_t ybytes = (size_t)n * 128 * sizeof(short);   // bf16 [n][128]
    u32* y1L = (u32*)p; p += ybytes;
    u32* y1N = (u32*)p; p += ybytes;
    float* h = (float*)p; p += (size_t)n * 128 * sizeof(float);
    float* dinvL = (float*)p; p += (size_t)n * sizeof(float);
    float* dinvN = (float*)p; p += (size_t)n * sizeof(float);
    float* bn_sum   = (float*)p; p += 128 * sizeof(float);
    float* bn_sumsq = (float*)p; p += 128 * sizeof(float);
    float* bn_scale = (float*)p; p += 128 * sizeof(float);
    float* bn_shift = (float*)p; p += 128 * sizeof(float);
    int* degL    = (int*)p; p += (size_t)n * sizeof(int);
    int* degN    = (int*)p; p += (size_t)n * sizeof(int);
    int* rowptrL = (int*)p; p += (size_t)(n + 1) * sizeof(int);
    int* rowptrN = (int*)p; p += (size_t)(n + 1) * sizeof(int);
    int* gcurL   = (int*)p; p += 64 * sizeof(int);
    int* gcurN   = (int*)p; p += 64 * sizeof(int);
    int* csrL    = (int*)p; p += (size_t)eL * sizeof(int);
    int* csrN    = (int*)p; p += (size_t)eN * sizeof(int);

    // staging aliases h (h is dead until gather1, which runs after binB)
    uint2* stagedL = (uint2*)h;
    uint2* stagedN = stagedL + eL;

    // layer-2 y tables ([n][64] bf16 each) reuse y1L space (exactly fits)
    u32* y2L = y1L;
    u32* y2N = y1L + (size_t)n * 32;

    hipMemsetAsync(degL, 0, (size_t)n * 2 * sizeof(int), stream);
    hipMemsetAsync(bn_sum, 0, 2 * 128 * sizeof(float), stream);

    const int emax = eL > eN ? eL : eN;
    count_deg_kernel<<<idiv_up(emax, 256), 256, 0, stream>>>(colL, colN, eL, eN, degL, degN);
    dinv_kernel<<<idiv_up(n, 256), 256, 0, stream>>>(degL, degN, dinvL, dinvN, n);
    scan_kernel<<<2, 1024, 0, stream>>>(degL, degN, n, rowptrL, rowptrN);
    init_gcur_kernel<<<1, 64, 0, stream>>>(rowptrL, rowptrN, gcurL, gcurN, nb);

    binA_kernel<<<dim3(idiv_up(emax, ACHUNK), 2), 256, 0, stream>>>(
        rowL, colL, eL, rowN, colN, eN, gcurL, gcurN, stagedL, stagedN, nb);
    binB_kernel<<<dim3(nb, 2), 256, 0, stream>>>(
        rowptrL, rowptrN, stagedL, stagedN, csrL, csrN, n);

    // layer 1
    gemm_kernel<128><<<dim3(idiv_up(n, 64), 2), 256, 0, stream>>>(
        x, n, W1L, W1N, dinvL, dinvN, y1L, y1N, nullptr, nullptr);

    // grid: 4 balanced sweeps per block (no grid-stride tail quantization)
    const int g128 = idiv_up(idiv_up(n, 4), 4);     // NPB=4
    gather_kernel<128, true><<<g128, 256, 0, stream>>>(
        rowptrL, csrL, rowptrN, csrN, y1L, y1N, dinvL, dinvN,
        b1L, b1N, h, n, bn_sum, bn_sumsq);

    bn_final_kernel<<<1, 128, 0, stream>>>(bn_sum, bn_sumsq, gamma, beta,
                                           bn_scale, bn_shift, 1.0f / (float)n);

    // layer 2 (BN+ReLU fused into GEMM A-load)
    gemm_kernel<64><<<dim3(idiv_up(n, 64), 2), 256, 0, stream>>>(
        h, n, W2L, W2N, dinvL, dinvN, y2L, y2N, bn_scale, bn_shift);

    const int g64 = idiv_up(idiv_up(n, 8), 2);      // NPB=8, 2 sweeps
    gather_kernel<64, false><<<g64, 256, 0, stream>>>(
        rowptrL, csrL, rowptrN, csrN, y2L, y2N, dinvL, dinvN,
        b2L, b2N, (float*)d_out, n, nullptr, nullptr);
}

// Round 8
// 883.909 us; speedup vs baseline: 1.1179x; 1.1179x over previous
//
#include <hip/hip_runtime.h>

typedef unsigned int u32;

static inline int idiv_up(int a, int b) { return (a + b - 1) / b; }

#define BSHIFT 11          // bucket width 2048 nodes
#define BW     2048
#define ACHUNK 8192        // edges per binA block

// ---------------- bf16 pack/unpack ----------------

__device__ __forceinline__ u32 pack_bf16_rne(float lo, float hi) {
    u32 ul = __float_as_uint(lo);
    u32 uh = __float_as_uint(hi);
    ul = (ul + 0x7fffu + ((ul >> 16) & 1u)) >> 16;
    uh = (uh + 0x7fffu + ((uh >> 16) & 1u));
    return (ul & 0xffffu) | (uh & 0xffff0000u);
}
__device__ __forceinline__ float bf16_lo(u32 u) { return __uint_as_float(u << 16); }
__device__ __forceinline__ float bf16_hi(u32 u) { return __uint_as_float(u & 0xffff0000u); }

// ---------------- degree histogram (int) ----------------

__global__ __launch_bounds__(256) void count_deg_kernel(
    const int* __restrict__ colL, const int* __restrict__ colN,
    int eL, int eN,
    int* __restrict__ degL, int* __restrict__ degN)
{
    int i = blockIdx.x * 256 + threadIdx.x;
    if (i < eL) atomicAdd(&degL[colL[i]], 1);
    if (i < eN) atomicAdd(&degN[colN[i]], 1);
}

__global__ __launch_bounds__(256) void dinv_kernel(
    const int* __restrict__ degL, const int* __restrict__ degN,
    float* __restrict__ dinvL, float* __restrict__ dinvN, int n)
{
    int i = blockIdx.x * 256 + threadIdx.x;
    if (i < n) {
        dinvL[i] = rsqrtf((float)degL[i] + 1.0f);   // +1 self loop
        dinvN[i] = rsqrtf((float)degN[i] + 1.0f);
    }
}

// ---------------- exclusive scan -> rowptr ----------------

__global__ __launch_bounds__(1024) void scan_kernel(
    const int* __restrict__ degL, const int* __restrict__ degN, int n,
    int* __restrict__ rowptrL, int* __restrict__ rowptrN)
{
    const int* deg = blockIdx.x ? degN : degL;
    int* rowptr    = blockIdx.x ? rowptrN : rowptrL;

    __shared__ int ls[1024];
    const int t = threadIdx.x;
    const int chunk = (n + 1023) / 1024;
    const int base = t * chunk;

    int s = 0;
    for (int i = 0; i < chunk; ++i) {
        int idx = base + i;
        if (idx < n) s += deg[idx];
    }
    ls[t] = s;
    __syncthreads();
    for (int off = 1; off < 1024; off <<= 1) {
        int add = (t >= off) ? ls[t - off] : 0;
        __syncthreads();
        ls[t] += add;
        __syncthreads();
    }
    int running = (t == 0) ? 0 : ls[t - 1];
    int total = ls[1023];
    for (int i = 0; i < chunk; ++i) {
        int idx = base + i;
        if (idx < n) {
            rowptr[idx] = running;
            running += deg[idx];
        }
    }
    if (t == 1023) rowptr[n] = total;
}

// ---------------- bucket cursor init: gcur[b] = rowptr[b*BW] ----------------

__global__ void init_gcur_kernel(
    const int* __restrict__ rowptrL, const int* __restrict__ rowptrN,
    int* __restrict__ gcurL, int* __restrict__ gcurN, int nb)
{
    int t = threadIdx.x;
    if (t < nb) {
        gcurL[t] = rowptrL[t << BSHIFT];
        gcurN[t] = rowptrN[t << BSHIFT];
    }
}

// ---------------- radix pass A: bin edges by dest-bucket ----------------

__global__ __launch_bounds__(256) void binA_kernel(
    const int* __restrict__ rowL, const int* __restrict__ colL, int eL,
    const int* __restrict__ rowN, const int* __restrict__ colN, int eN,
    int* __restrict__ gcurL, int* __restrict__ gcurN,
    uint2* __restrict__ stagedL, uint2* __restrict__ stagedN, int nb)
{
    const int adj = blockIdx.y;
    const int* rowA = adj ? rowN : rowL;
    const int* colA = adj ? colN : colL;
    const int e     = adj ? eN   : eL;
    int* gcur       = adj ? gcurN : gcurL;
    uint2* staged   = adj ? stagedN : stagedL;

    __shared__ int hist[64];
    __shared__ int base[64];
    const int t = threadIdx.x;
    if (t < 64) hist[t] = 0;
    __syncthreads();

    const int i0 = blockIdx.x * ACHUNK;
    const int i1 = min(i0 + ACHUNK, e);

    for (int i = i0 + t; i < i1; i += 256)
        atomicAdd(&hist[colA[i] >> BSHIFT], 1);
    __syncthreads();

    if (t < 64) {
        int cnt = hist[t];
        if (t < nb && cnt > 0) base[t] = atomicAdd(&gcur[t], cnt);
    }
    __syncthreads();
    if (t < 64) hist[t] = 0;    // reuse as per-bucket offset
    __syncthreads();

    for (int i = i0 + t; i < i1; i += 256) {
        int c = colA[i], r = rowA[i];
        int b = c >> BSHIFT;
        int pos = base[b] + atomicAdd(&hist[b], 1);
        staged[pos] = make_uint2((u32)c, (u32)r);
    }
}

// ---------------- radix pass B: place within bucket (LDS cursors) ----------------

__global__ __launch_bounds__(256) void binB_kernel(
    const int* __restrict__ rowptrL, const int* __restrict__ rowptrN,
    const uint2* __restrict__ stagedL, const uint2* __restrict__ stagedN,
    int* __restrict__ csrL, int* __restrict__ csrN, int n)
{
    const int adj = blockIdx.y;
    const int* rowptr   = adj ? rowptrN : rowptrL;
    const uint2* staged = adj ? stagedN : stagedL;
    int* csr            = adj ? csrN    : csrL;

    __shared__ int lcur[BW];
    const int lo = blockIdx.x << BSHIFT;
    const int hi = min(lo + BW, n);
    const int t = threadIdx.x;

    for (int i = lo + t; i < hi; i += 256) lcur[i - lo] = rowptr[i];
    __syncthreads();

    const int s0 = rowptr[lo], s1 = rowptr[hi];
    for (int i = s0 + t; i < s1; i += 256) {
        uint2 er = staged[i];
        int p = atomicAdd(&lcur[(int)er.x - lo], 1);
        csr[p] = (int)er.y;
    }
}

// ---------------- GEMM: y(bf16) = (A @ W) * dinv[row] ----------------

template<int NC>
__global__ __launch_bounds__(256) void gemm_kernel(
    const float* __restrict__ A, int n,
    const float* __restrict__ Wa, const float* __restrict__ Wb,
    const float* __restrict__ dinva, const float* __restrict__ dinvb,
    u32* __restrict__ ya, u32* __restrict__ yb,
    const float* __restrict__ bn_scale, const float* __restrict__ bn_shift)
{
    constexpr int K   = 128;
    constexpr int TR  = 64;        // rows per block
    constexpr int CG  = NC / 4;    // float4 column groups
    constexpr int TY  = 256 / CG;  // thread-row groups
    constexpr int RPT = TR / TY;   // rows per thread

    __shared__ float xs[TR][K];

    const float* W    = blockIdx.y ? Wb    : Wa;
    const float* dinv = blockIdx.y ? dinvb : dinva;
    u32* y            = blockIdx.y ? yb    : ya;

    const int row0 = blockIdx.x * TR;
    const int t = threadIdx.x;

    const float4* A4 = (const float4*)A;
    #pragma unroll
    for (int i = 0; i < (TR * (K / 4)) / 256; ++i) {
        int fl = i * 256 + t;
        int r  = fl >> 5;       // K/4 == 32
        int c4 = fl & 31;
        float4 v = make_float4(0.f, 0.f, 0.f, 0.f);
        int rr = row0 + r;
        if (rr < n) v = A4[(size_t)rr * 32 + c4];
        if (bn_scale) {
            float4 sc = ((const float4*)bn_scale)[c4];
            float4 sh = ((const float4*)bn_shift)[c4];
            v.x = fmaxf(v.x * sc.x + sh.x, 0.f);
            v.y = fmaxf(v.y * sc.y + sh.y, 0.f);
            v.z = fmaxf(v.z * sc.z + sh.z, 0.f);
            v.w = fmaxf(v.w * sc.w + sh.w, 0.f);
        }
        *(float4*)&xs[r][c4 * 4] = v;
    }
    __syncthreads();

    const int cg = t % CG;
    const int ty = t / CG;

    float4 accv[RPT];
    #pragma unroll
    for (int r = 0; r < RPT; ++r) accv[r] = make_float4(0.f, 0.f, 0.f, 0.f);

    const float4* W4 = (const float4*)W;
    for (int k = 0; k < K; k += 4) {
        float4 w0 = W4[(size_t)(k + 0) * CG + cg];
        float4 w1 = W4[(size_t)(k + 1) * CG + cg];
        float4 w2 = W4[(size_t)(k + 2) * CG + cg];
        float4 w3 = W4[(size_t)(k + 3) * CG + cg];
        #pragma unroll
        for (int r = 0; r < RPT; ++r) {
            float4 a = *(const float4*)&xs[ty * RPT + r][k];
            accv[r].x += a.x * w0.x; accv[r].y += a.x * w0.y; accv[r].z += a.x * w0.z; accv[r].w += a.x * w0.w;
            accv[r].x += a.y * w1.x; accv[r].y += a.y * w1.y; accv[r].z += a.y * w1.z; accv[r].w += a.y * w1.w;
            accv[r].x += a.z * w2.x; accv[r].y += a.z * w2.y; accv[r].z += a.z * w2.z; accv[r].w += a.z * w2.w;
            accv[r].x += a.w * w3.x; accv[r].y += a.w * w3.y; accv[r].z += a.w * w3.z; accv[r].w += a.w * w3.w;
        }
    }

    #pragma unroll
    for (int r = 0; r < RPT; ++r) {
        int rr = row0 + ty * RPT + r;
        if (rr < n) {
            float dv = dinv[rr];
            float4 o = accv[r];
            o.x *= dv; o.y *= dv; o.z *= dv; o.w *= dv;
            uint2 pk;
            pk.x = pack_bf16_rne(o.x, o.y);
            pk.y = pack_bf16_rne(o.z, o.w);
            ((uint2*)y)[(size_t)rr * CG + cg] = pk;
        }
    }
}

// ---------------- neighbor-sum: U=8 masked unroll + index-batch pipeline ----
// Broadcast idx loads (cheap, L2-hit), 8 independent row loads in flight,
// next index batch prefetched under the row loads, no scalar tail.

template<int CHW>
__device__ __forceinline__ void gather_row_sum(
    const int* __restrict__ rowptr, const int* __restrict__ csr,
    const u32* __restrict__ y, int node, int c, float& s0, float& s1)
{
    u32 self = y[(size_t)node * CHW + c];
    s0 += bf16_lo(self); s1 += bf16_hi(self);

    int j0 = rowptr[node], end = rowptr[node + 1];
    if (j0 >= end) return;

    int idx[8];
    #pragma unroll
    for (int k = 0; k < 8; ++k) idx[k] = csr[min(j0 + k, end - 1)];

    for (int base = j0; base < end; base += 8) {
        u32 a[8];
        #pragma unroll
        for (int k = 0; k < 8; ++k) a[k] = y[(size_t)idx[k] * CHW + c];

        int nbase = base + 8;
        if (nbase < end) {
            #pragma unroll
            for (int k = 0; k < 8; ++k) idx[k] = csr[min(nbase + k, end - 1)];
        }

        #pragma unroll
        for (int k = 0; k < 8; ++k) {
            float m = (base + k < end) ? 1.0f : 0.0f;
            s0 = fmaf(m, bf16_lo(a[k]), s0);
            s1 = fmaf(m, bf16_hi(a[k]), s1);
        }
    }
}

// ---------------- fused gather + combine (+bias, BN stats) ----------------

template<int CH, bool STATS>
__global__ __launch_bounds__(256) void gather_kernel(
    const int* __restrict__ rowptrL, const int* __restrict__ csrL,
    const int* __restrict__ rowptrN, const int* __restrict__ csrN,
    const u32* __restrict__ yL, const u32* __restrict__ yN,
    const float* __restrict__ dinvL, const float* __restrict__ dinvN,
    const float* __restrict__ bL, const float* __restrict__ bN,
    float* __restrict__ out, int n,
    float* __restrict__ bn_sum, float* __restrict__ bn_sumsq)
{
    constexpr int CHW = CH / 2;         // u32 lanes per node
    constexpr int NPB = 256 / CHW;      // nodes per block-iteration
    const int c  = threadIdx.x % CHW;
    const int ns = threadIdx.x / CHW;
    const float2 blv = ((const float2*)bL)[c];
    const float2 bnv = ((const float2*)bN)[c];

    float s0 = 0.f, s1 = 0.f, q0 = 0.f, q1 = 0.f;

    for (int node0 = blockIdx.x * NPB; node0 < n; node0 += gridDim.x * NPB) {
        const int node = node0 + ns;
        if (node < n) {
            float sL0 = 0.f, sL1 = 0.f, sN0 = 0.f, sN1 = 0.f;
            gather_row_sum<CHW>(rowptrL, csrL, yL, node, c, sL0, sL1);
            gather_row_sum<CHW>(rowptrN, csrN, yN, node, c, sN0, sN1);

            float dl = dinvL[node], dn = dinvN[node];
            float v0 = dl * sL0 + blv.x + 0.5f * (dn * sN0 + bnv.x);
            float v1 = dl * sL1 + blv.y + 0.5f * (dn * sN1 + bnv.y);
            ((float2*)out)[(size_t)node * CHW + c] = make_float2(v0, v1);
            if constexpr (STATS) { s0 += v0; s1 += v1; q0 += v0 * v0; q1 += v1 * v1; }
        }
    }

    if constexpr (STATS) {
        __shared__ float4 ls[256];
        ls[threadIdx.x] = make_float4(s0, s1, q0, q1);
        __syncthreads();
        if (threadIdx.x < CHW) {
            float4 a = ls[threadIdx.x];
            #pragma unroll
            for (int i = 1; i < NPB; ++i) {
                float4 b = ls[threadIdx.x + i * CHW];
                a.x += b.x; a.y += b.y; a.z += b.z; a.w += b.w;
            }
            atomicAdd(&bn_sum[2 * threadIdx.x + 0], a.x);
            atomicAdd(&bn_sum[2 * threadIdx.x + 1], a.y);
            atomicAdd(&bn_sumsq[2 * threadIdx.x + 0], a.z);
            atomicAdd(&bn_sumsq[2 * threadIdx.x + 1], a.w);
        }
    }
}

__global__ void bn_final_kernel(
    const float* __restrict__ sum, const float* __restrict__ sumsq,
    const float* __restrict__ gamma, const float* __restrict__ beta,
    float* __restrict__ scale, float* __restrict__ shift, float inv_n)
{
    int c = threadIdx.x;
    float mean = sum[c] * inv_n;
    float var  = sumsq[c] * inv_n - mean * mean;
    float sc = gamma[c] * rsqrtf(var + 1e-5f);
    scale[c] = sc;
    shift[c] = beta[c] - mean * sc;
}

// ---------------- launch ----------------

extern "C" void kernel_launch(void* const* d_in, const int* in_sizes, int n_in,
                              void* d_out, int out_size, void* d_ws, size_t ws_size,
                              hipStream_t stream)
{
    const float* x     = (const float*)d_in[0];
    const int*   adjL  = (const int*)d_in[1];   // adj_low
    const int*   adjN  = (const int*)d_in[3];   // adj_nd_low (adj_high/nd_high unused)
    const float* W1L   = (const float*)d_in[5];
    const float* b1L   = (const float*)d_in[6];
    const float* W1N   = (const float*)d_in[7];
    const float* b1N   = (const float*)d_in[8];
    const float* gamma = (const float*)d_in[9];
    const float* beta  = (const float*)d_in[10];
    const float* W2L   = (const float*)d_in[11];
    const float* b2L   = (const float*)d_in[12];
    const float* W2N   = (const float*)d_in[13];
    const float* b2N   = (const float*)d_in[14];

    const int n  = in_sizes[0] / 128;
    const int eL = in_sizes[1] / 2;
    const int eN = in_sizes[3] / 2;
    const int* rowL = adjL;  const int* colL = adjL + eL;
    const int* rowN = adjN;  const int* colN = adjN + eN;
    const int nb = idiv_up(n, BW);

    char* p = (char*)d_ws;
    const size_t ybytes = (size_t)n * 128 * sizeof(short);   // bf16 [n][128]
    u32* y1L = (u32*)p; p += ybytes;
    u32* y1N = (u32*)p; p += ybytes;
    float* h = (float*)p; p += (size_t)n * 128 * sizeof(float);
    float* dinvL = (float*)p; p += (size_t)n * sizeof(float);
    float* dinvN = (float*)p; p += (size_t)n * sizeof(float);
    float* bn_sum   = (float*)p; p += 128 * sizeof(float);
    float* bn_sumsq = (float*)p; p += 128 * sizeof(float);
    float* bn_scale = (float*)p; p += 128 * sizeof(float);
    float* bn_shift = (float*)p; p += 128 * sizeof(float);
    int* degL    = (int*)p; p += (size_t)n * sizeof(int);
    int* degN    = (int*)p; p += (size_t)n * sizeof(int);
    int* rowptrL = (int*)p; p += (size_t)(n + 1) * sizeof(int);
    int* rowptrN = (int*)p; p += (size_t)(n + 1) * sizeof(int);
    int* gcurL   = (int*)p; p += 64 * sizeof(int);
    int* gcurN   = (int*)p; p += 64 * sizeof(int);
    int* csrL    = (int*)p; p += (size_t)eL * sizeof(int);
    int* csrN    = (int*)p; p += (size_t)eN * sizeof(int);

    // staging aliases h (h is dead until gather1, which runs after binB)
    uint2* stagedL = (uint2*)h;
    uint2* stagedN = stagedL + eL;

    // layer-2 y tables ([n][64] bf16 each) reuse y1L space (exactly fits)
    u32* y2L = y1L;
    u32* y2N = y1L + (size_t)n * 32;

    hipMemsetAsync(degL, 0, (size_t)n * 2 * sizeof(int), stream);
    hipMemsetAsync(bn_sum, 0, 2 * 128 * sizeof(float), stream);

    const int emax = eL > eN ? eL : eN;
    count_deg_kernel<<<idiv_up(emax, 256), 256, 0, stream>>>(colL, colN, eL, eN, degL, degN);
    dinv_kernel<<<idiv_up(n, 256), 256, 0, stream>>>(degL, degN, dinvL, dinvN, n);
    scan_kernel<<<2, 1024, 0, stream>>>(degL, degN, n, rowptrL, rowptrN);
    init_gcur_kernel<<<1, 64, 0, stream>>>(rowptrL, rowptrN, gcurL, gcurN, nb);

    binA_kernel<<<dim3(idiv_up(emax, ACHUNK), 2), 256, 0, stream>>>(
        rowL, colL, eL, rowN, colN, eN, gcurL, gcurN, stagedL, stagedN, nb);
    binB_kernel<<<dim3(nb, 2), 256, 0, stream>>>(
        rowptrL, rowptrN, stagedL, stagedN, csrL, csrN, n);

    // layer 1
    gemm_kernel<128><<<dim3(idiv_up(n, 64), 2), 256, 0, stream>>>(
        x, n, W1L, W1N, dinvL, dinvN, y1L, y1N, nullptr, nullptr);

    gather_kernel<128, true><<<4096, 256, 0, stream>>>(
        rowptrL, csrL, rowptrN, csrN, y1L, y1N, dinvL, dinvN,
        b1L, b1N, h, n, bn_sum, bn_sumsq);

    bn_final_kernel<<<1, 128, 0, stream>>>(bn_sum, bn_sumsq, gamma, beta,
                                           bn_scale, bn_shift, 1.0f / (float)n);

    // layer 2 (BN+ReLU fused into GEMM A-load)
    gemm_kernel<64><<<dim3(idiv_up(n, 64), 2), 256, 0, stream>>>(
        h, n, W2L, W2N, dinvL, dinvN, y2L, y2N, bn_scale, bn_shift);

    gather_kernel<64, false><<<4096, 256, 0, stream>>>(
        rowptrL, csrL, rowptrN, csrN, y2L, y2N, dinvL, dinvN,
        b2L, b2N, (float*)d_out, n, nullptr, nullptr);
}